// Round 1
// 1363.454 us; speedup vs baseline: 1.4131x; 1.4131x over previous
//
#include <hip/hip_runtime.h>
#include <hip/hip_bf16.h>

// RelPartialLearnableMultiHeadAttn (Transformer-XL) on MI355X.
// Shapes: QLEN=KLEN=RLEN=2048, BSZ=2, NH=16, DH=64, DM=1024. SCALE=0.125.
// R4: BD is no longer materialized. The rel-shifted BD[q][k] is
//   k <= q   : G[q][2047 + (k-q)]        (G = Q.Rk^T)
//   k == q+1 : 0
//   k >= q+2 : G[q+1][(k-q) - 2]
// Per wave (16 q-rows) and per 16-wide k-tile the needed G entries lie in a
// 31-column band whose center slides +16 per tile -> one fresh band MFMA per
// step (previous tile reused as the other window half) + a same-quad shuffle
// reconstructs BD in-register. bd_kernel and the 512 MiB BD round trip are
// deleted. Pass-B __syncthreads removed (Plds slice is per-wave private).

#define QL 2048
#define KL 2048
#define RL 2048
#define BS 2
#define NHD 16
#define DH 64
#define DM 1024

typedef __hip_bfloat16 bf16;
typedef short v8s __attribute__((ext_vector_type(8)));
typedef float v4f __attribute__((ext_vector_type(4)));

__device__ __forceinline__ bf16 f2b(float x) { return __float2bfloat16(x); }
__device__ __forceinline__ short f2s(float x) {
    return __builtin_bit_cast(short, __float2bfloat16(x));
}

// ---------------------------------------------------------------------------
// 64x64-tile GEMM, C = A(MxK) @ B(KxN), A/B row-major FLOAT32; bf16 MFMA.
// EPI 0: f32 C write. EPI 1: qkv scatter (+r_r_bias into Qb; Wv transposed),
// bf16 out. EPI 2: Rk scatter [n][r][d], bf16 out.
// ---------------------------------------------------------------------------
template <int EPI>
__global__ __launch_bounds__(256) void gemm64f(
    const float* __restrict__ A, const float* __restrict__ B,
    int M, int N, int K,
    float* __restrict__ C,
    bf16* __restrict__ Qb, bf16* __restrict__ Wk, bf16* __restrict__ Wvt,
    bf16* __restrict__ Rk, const float* __restrict__ rrb)
{
    __shared__ short As[64][40];   // +8 pad; row stride 80 B (16B-aligned)
    __shared__ short Bs[64][40];   // transposed: Bs[n][k]
    const int n0 = blockIdx.x * 64, m0 = blockIdx.y * 64;
    const int t = threadIdx.x, w = t >> 6, lane = t & 63;
    const int quad = lane >> 4, lr = lane & 15;

    v4f acc[4] = {};
    for (int k0 = 0; k0 < K; k0 += 32) {
        {   // A tile 64x32 f32 -> bf16 LDS: row = t>>2, 8 floats per thread
            const int row = t >> 2, cg = (t & 3) << 3;
            const float* ap = A + (size_t)(m0 + row) * K + k0 + cg;
            float4 a0 = *(const float4*)ap;
            float4 a1 = *(const float4*)(ap + 4);
            v8s pk;
            pk[0] = f2s(a0.x); pk[1] = f2s(a0.y); pk[2] = f2s(a0.z); pk[3] = f2s(a0.w);
            pk[4] = f2s(a1.x); pk[5] = f2s(a1.y); pk[6] = f2s(a1.z); pk[7] = f2s(a1.w);
            *(v8s*)&As[row][cg] = pk;
            // B tile 32x64 f32 -> transposed bf16 LDS: kk = t>>3, 8 floats
            const int kk = t >> 3, ng = (t & 7) << 3;
            const float* bp = B + (size_t)(k0 + kk) * N + n0 + ng;
            float4 b0 = *(const float4*)bp;
            float4 b1 = *(const float4*)(bp + 4);
            Bs[ng + 0][kk] = f2s(b0.x); Bs[ng + 1][kk] = f2s(b0.y);
            Bs[ng + 2][kk] = f2s(b0.z); Bs[ng + 3][kk] = f2s(b0.w);
            Bs[ng + 4][kk] = f2s(b1.x); Bs[ng + 5][kk] = f2s(b1.y);
            Bs[ng + 6][kk] = f2s(b1.z); Bs[ng + 7][kk] = f2s(b1.w);
        }
        __syncthreads();
        v8s af = *(const v8s*)&As[16 * w + lr][quad * 8];
#pragma unroll
        for (int ct = 0; ct < 4; ++ct) {
            v8s bfm = *(const v8s*)&Bs[ct * 16 + lr][quad * 8];
            acc[ct] = __builtin_amdgcn_mfma_f32_16x16x32_bf16(af, bfm, acc[ct], 0, 0, 0);
        }
        __syncthreads();
    }

#pragma unroll
    for (int ct = 0; ct < 4; ++ct) {
#pragma unroll
        for (int r = 0; r < 4; ++r) {
            const int gm = m0 + 16 * w + quad * 4 + r;   // C row
            const int gn = n0 + ct * 16 + lr;            // C col
            float v = acc[ct][r];
            if constexpr (EPI == 0) {
                C[(size_t)gm * N + gn] = v;
            } else if constexpr (EPI == 1) {
                const int q = gm >> 1, b = gm & 1;       // w rows are (q, b)
                const int sec = gn >> 10, idx = gn & 1023;
                const int n = idx >> 6, d = idx & 63;
                const size_t bn = (size_t)(b * NHD + n);
                if (sec == 0) {
                    v += rrb[n * 64 + d];                // Qb = wq + r_r_bias
                    Qb[(bn * QL + q) * DH + d] = f2b(v);
                } else if (sec == 1) {
                    Wk[(bn * KL + q) * DH + d] = f2b(v);
                } else {
                    Wvt[(bn * DH + d) * KL + q] = f2b(v); // transposed [d][k]
                }
            } else {  // EPI == 2 : Rk[n][r][d]
                const int n = gn >> 6, d = gn & 63;
                Rk[((size_t)n * RL + gm) * DH + d] = f2b(v);
            }
        }
    }
}

// ---------------------------------------------------------------------------
// Fused BD + scores + softmax + coverage + PV per (b,n, 64-row q block).
// Pass A: AC via MFMA, BD via sliding-band MFMA + same-quad shuffle ->
//         per-lane online (m,l), butterfly merge within each quad.
// Pass B: recompute scores identically, write normalized P (f32 coverage),
//         round-trip P (bf16) through per-wave-private LDS, accumulate P@Wv.
// ---------------------------------------------------------------------------
__global__ __launch_bounds__(256) void attn_kernel(
    const bf16* __restrict__ Qb, const bf16* __restrict__ Wk,
    const bf16* __restrict__ Wvt, const bf16* __restrict__ Rk,
    const int* __restrict__ mask,
    float* __restrict__ cov, float* __restrict__ AV)
{
    __shared__ short Plds[4][16][32];
    __shared__ int mlds[KL];
    const int bn = blockIdx.y, b = bn >> 4, n = bn & 15;
    const int t = threadIdx.x, w = t >> 6, lane = t & 63;
    const int quad = lane >> 4, lr = lane & 15;
    const int q0 = blockIdx.x * 64 + 16 * w;   // wave's 16-row q-tile base

    for (int i = t; i < KL; i += 256) mlds[i] = mask[i * BS + b];
    __syncthreads();

    // Q fragments: rows q0+lr, and shifted rows q0+1+lr (clamped; the clamped
    // row is only reachable for q=2047 / k>=2049 which never occurs).
    const bf16* qbase = Qb + ((size_t)bn * QL + q0 + lr) * DH;
    const v8s aq0 = *(const v8s*)(qbase + quad * 8);
    const v8s aq1 = *(const v8s*)(qbase + 32 + quad * 8);
    int qs = q0 + 1 + lr; qs = qs > QL - 1 ? QL - 1 : qs;
    const bf16* qsb = Qb + ((size_t)bn * QL + qs) * DH;
    const v8s as0 = *(const v8s*)(qsb + quad * 8);
    const v8s as1 = *(const v8s*)(qsb + 32 + quad * 8);

    const bf16* kbase = Wk + (size_t)bn * KL * DH;
    const bf16* rkb   = Rk + (size_t)n * RL * DH;
    float* covb = cov + (size_t)bn * QL * KL;

    const v4f vzero = {};

    // 16x16 tile of G = Q.Rk^T over Rk columns [cb, cb+16) (rows clamped;
    // out-of-range columns are never selected by the band logic).
    auto band = [&](int cb, v8s a0, v8s a1) -> v4f {
        int rrow = cb + lr;
        rrow = rrow < 0 ? 0 : (rrow > RL - 1 ? RL - 1 : rrow);
        const bf16* rp = rkb + (size_t)rrow * DH;
        v8s b0 = *(const v8s*)(rp + quad * 8);
        v8s b1 = *(const v8s*)(rp + 32 + quad * 8);
        v4f a = {};
        a = __builtin_amdgcn_mfma_f32_16x16x32_bf16(a0, b0, a, 0, 0, 0);
        a = __builtin_amdgcn_mfma_f32_16x16x32_bf16(a1, b1, a, 0, 0, 0);
        return a;
    };

    // Sliding band state. Band A (k<=q): G rows q, window center 2047+(kb-q0).
    // Band B (k>=q+2): G rows q+1, window center (kb-q0)-2. Each step computes
    // one fresh 16-col tile; previous tile is the other half of the window.
    v4f TA0, TA1, TB0, TB1;

    // Masked, scaled score tile for k-tile [kb, kb+16); updates band state.
    auto scores = [&](int kb, float* s) {
        const bool useA = (kb <= q0);   // wave-uniform
        const bool useB = (kb >= q0);
        if (useA) TA1 = band(kb - q0 + 2047, aq0, aq1);
        if (useB) TB1 = band(kb - q0 - 2,   as0, as1);
        const bf16* krow = kbase + (size_t)(kb + lr) * DH;
        v8s bk0 = *(const v8s*)(krow + quad * 8);
        v8s bk1 = *(const v8s*)(krow + 32 + quad * 8);
        v4f ac = {};
        ac = __builtin_amdgcn_mfma_f32_16x16x32_bf16(aq0, bk0, ac, 0, 0, 0);
        ac = __builtin_amdgcn_mfma_f32_16x16x32_bf16(aq1, bk1, ac, 0, 0, 0);
        const bool msk = mlds[kb + lr] != 0;
#pragma unroll
        for (int r = 0; r < 4; ++r) {
            const int rho = quad * 4 + r;          // tile-local q row
            const int o = lr - rho;                // col - row, in [-15,15]
            const int dk = (kb - q0) + o;          // k - q
            const int src = (lane & 48) | (o & 15);
            float vA = 0.f, vB = 0.f;
            if (useA) {
                float x0 = __shfl(TA0[r], src, 64);
                float x1 = __shfl(TA1[r], src, 64);
                vA = (o >= 0) ? x1 : x0;
            }
            if (useB) {
                float x0 = __shfl(TB0[r], src, 64);
                float x1 = __shfl(TB1[r], src, 64);
                vB = (o >= 0) ? x1 : x0;
            }
            const float bd = (dk <= 0) ? vA : ((dk == 1) ? 0.f : vB);
            s[r] = msk ? -1.0e30f : (ac[r] + bd) * 0.125f;
        }
        TA0 = TA1;
        TB0 = TB1;
    };

    // ---- pass A: online max/sum ----
    float pm[4], pl[4];
#pragma unroll
    for (int r = 0; r < 4; ++r) { pm[r] = -3.0e38f; pl[r] = 0.f; }
    TA0 = band(2047 - q0 - 16, aq0, aq1);   // init window low half
    TA1 = vzero; TB0 = vzero; TB1 = vzero;  // TB0 unused until kb>q0
    for (int kb = 0; kb < KL; kb += 16) {
        float s[4];
        scores(kb, s);
#pragma unroll
        for (int r = 0; r < 4; ++r) {
            const float nm = fmaxf(pm[r], s[r]);
            pl[r] = pl[r] * __expf(pm[r] - nm) + __expf(s[r] - nm);
            pm[r] = nm;
        }
    }
    // merge (m,l) across the 16 lanes of each quad
#pragma unroll
    for (int r = 0; r < 4; ++r) {
        float m = pm[r], l = pl[r];
#pragma unroll
        for (int off = 1; off < 16; off <<= 1) {
            float om = __shfl_xor(m, off, 64);
            float ol = __shfl_xor(l, off, 64);
            float nm = fmaxf(m, om);
            l = l * __expf(m - nm) + ol * __expf(om - nm);
            m = nm;
        }
        pm[r] = m;
        pl[r] = (l > 0.f) ? 1.f / l : 0.f;
    }

    // ---- pass B: normalized P write (f32 coverage) + PV ----
    v4f accv[4] = {};
    TA0 = band(2047 - q0 - 16, aq0, aq1);
    TA1 = vzero; TB0 = vzero; TB1 = vzero;
    for (int kb = 0; kb < KL; kb += 16) {
        float s[4];
        scores(kb, s);
        const int tt = (kb >> 4) & 1;
#pragma unroll
        for (int r = 0; r < 4; ++r) {
            const int q = q0 + quad * 4 + r;
            const float p = __expf(s[r] - pm[r]) * pl[r];
            covb[(size_t)q * KL + kb + lr] = p;
            Plds[w][quad * 4 + r][tt * 16 + lr] = f2s(p);
        }
        if (tt == 1) {
            // Plds[w] is wave-private: in-wave DS ordering suffices, no barrier
            v8s ap = *(const v8s*)&Plds[w][lr][quad * 8];
            const int k0 = kb & ~31;
#pragma unroll
            for (int dt = 0; dt < 4; ++dt) {
                const bf16* vrow = Wvt + ((size_t)bn * DH + dt * 16 + lr) * KL + k0 + quad * 8;
                v8s bv = *(const v8s*)vrow;
                accv[dt] = __builtin_amdgcn_mfma_f32_16x16x32_bf16(ap, bv, accv[dt], 0, 0, 0);
            }
        }
    }

    // attn_vec: AV[q][b][n*64+d]  (f32)
#pragma unroll
    for (int dt = 0; dt < 4; ++dt) {
#pragma unroll
        for (int r = 0; r < 4; ++r) {
            const int q = q0 + quad * 4 + r;
            AV[((size_t)q * BS + b) * DM + n * DH + dt * 16 + lr] = accv[dt][r];
        }
    }
}

extern "C" void kernel_launch(void* const* d_in, const int* in_sizes, int n_in,
                              void* d_out, int out_size, void* d_ws, size_t ws_size,
                              hipStream_t stream)
{
    const float* w     = (const float*)d_in[0];   // (2048, 2, 1024) f32
    const float* r     = (const float*)d_in[1];   // (2048, 1024) f32
    const int*   mask  = (const int*)d_in[2];     // (2048, 2) bool->int32
    const float* qkvw  = (const float*)d_in[3];   // (1024, 3072) f32
    const float* rnetw = (const float*)d_in[4];   // (1024, 1024) f32
    const float* ow    = (const float*)d_in[5];   // (1024, 1024) f32
    const float* rrb   = (const float*)d_in[7];   // (16, 64) f32 (d_in[6] unused: ref bug)

    char* ws = (char*)d_ws;
    bf16*  Qb  = (bf16*)(ws);                        // [b][n][q][d] bf16   8 MiB
    bf16*  Wk  = (bf16*)(ws + ((size_t)8  << 20));   // [b][n][k][d] bf16   8 MiB
    bf16*  Wvt = (bf16*)(ws + ((size_t)16 << 20));   // [b][n][d][k] bf16   8 MiB
    bf16*  Rk  = (bf16*)(ws + ((size_t)24 << 20));   // [n][r][d] bf16      4 MiB
    float* AV  = (float*)(ws + ((size_t)28 << 20));  // [q][b][1024] f32   16 MiB
    // total ws use: 44 MiB

    float* out_main = (float*)d_out;                      // (2048, 2, 1024) f32
    float* out_cov  = out_main + (size_t)QL * BS * DM;    // (2,16,2048,2048) f32

    // 1) heads = w @ qkv_w, scatter Qb(+bias)/Wk/Wvt
    gemm64f<1><<<dim3(48, 64), 256, 0, stream>>>(w, qkvw, 4096, 3072, 1024,
                                                 nullptr, Qb, Wk, Wvt, nullptr, rrb);
    // 2) Rk = r @ r_net_w
    gemm64f<2><<<dim3(16, 32), 256, 0, stream>>>(r, rnetw, 2048, 1024, 1024,
                                                 nullptr, nullptr, nullptr, nullptr, Rk, nullptr);
    // 3) fused BD + scores + softmax + coverage + PV
    attn_kernel<<<dim3(32, 32), 256, 0, stream>>>(Qb, Wk, Wvt, Rk, mask, out_cov, AV);
    // 4) output = attn_vec @ o_w
    gemm64f<0><<<dim3(16, 64), 256, 0, stream>>>(AV, ow, 4096, 1024, 1024,
                                                 out_main, nullptr, nullptr, nullptr, nullptr, nullptr);
}